// Round 13
// baseline (74.928 us; speedup 1.0000x reference)
//
#include <hip/hip_runtime.h>
#include <math.h>

// Hexagonal sensor photon binning — R13: 3-deep ring x chunked layout.
// R12 (chunked, 2-deep) = 68.6us profiled; still ~3.5 TB/s beyond-L2 reads vs
// 6.3 composite ceiling, all pipes <30%. R10's deep ring was nulled on the
// locality-hostile grid-stride walk only. This round combines the two:
// contiguous per-block chunks + 3-slot prefetch ring (144B/lane in flight,
// vmcnt wait covered by ~2 groups of VALU across 32 resident waves/CU).
//  * 512 blocks x 1024 threads, 36 data VGPR + ~20 live -> 2 blocks/CU
//  * nt 16B loads, closed-form hex index, LDS hist
//  * store-flush to private rows + rowgroup reduce (no atomics in bin kernel)

typedef float f32x4 __attribute__((ext_vector_type(4)));

#define BIN_BLOCKS  512
#define BIN_THREADS 1024
#define RED_GROUP   32    // rows per reduce block

__global__ void hex_zero_kernel(float* __restrict__ p, int n) {
    int i = blockIdx.x * blockDim.x + threadIdx.x;
    if (i < n) p[i] = 0.0f;
}

__global__ __launch_bounds__(256) void hex_reduce_kernel(
    const float* __restrict__ partials, float* __restrict__ out,
    int n_pixels, int nrows)
{
    int pix = blockIdx.x * blockDim.x + threadIdx.x;
    if (pix >= n_pixels) return;
    int r0 = blockIdx.y * RED_GROUP;
    int r1 = min(r0 + RED_GROUP, nrows);
    float s = 0.0f;
    const float* p = partials + (size_t)r0 * n_pixels + pix;
    #pragma unroll 8
    for (int r = r0; r < r1; ++r) {
        s += *p;
        p += n_pixels;
    }
    atomicAdd(&out[pix], s);
}

__global__ __launch_bounds__(BIN_THREADS) void hex_bin_kernel(
    const float* __restrict__ x,
    const float* __restrict__ y,
    const float* __restrict__ vals,
    const float* __restrict__ hex_size_p,
    const float* __restrict__ q_off_p,
    const float* __restrict__ r_off_p,
    const int*   __restrict__ q_min_p,
    const int*   __restrict__ r_min_p,
    int Rh, int n_pixels, int n_photons,
    float* __restrict__ flush_dst,
    int flush_mode)   // 2 = private row store, 0 = direct atomic fallback
{
    extern __shared__ float hist[];  // n_pixels floats
    for (int i = threadIdx.x; i < n_pixels; i += blockDim.x) hist[i] = 0.0f;
    __syncthreads();

    const float inv_h = 1.0f / hex_size_p[0];
    const float A  = 0.57735026918962576f * inv_h;
    const float Bn = -(0.33333333333333333f * inv_h);
    const float C  = 0.66666666666666667f * inv_h;
    const float qc = -q_off_p[0];
    const float rc = -r_off_p[0];
    const int   qmin = q_min_p[0];
    const int   rmin = r_min_p[0];

    const unsigned twoR = (unsigned)(2 * Rh);
    const int Rp1 = Rh + 1;

    auto process = [&](float xf, float yf, float vf) {
        float q = fmaf(A, xf, fmaf(Bn, yf, qc));
        float r = fmaf(C, yf, rc);
        float t = q + r;                  // s = -t, sr = -rintf(t)
        float qr = rintf(q);
        float rr = rintf(r);
        float tr = rintf(t);
        float qd = fabsf(qr - q);
        float rd = fabsf(rr - r);
        float td = fabsf(tr - t);         // == sd
        float q2 = (qd > rd && qd > td) ? (tr - rr) : qr;
        float r2 = (rd > qd && rd > td) ? (tr - qr) : rr;
        int qi = (int)q2 - qmin;
        int ri = (int)r2 - rmin;
        int d  = qi + ri;
        if ((unsigned)qi <= twoR && (unsigned)ri <= twoR &&
            (unsigned)(d - Rh) <= twoR) {
            int u  = max(qi - Rh, 0);
            int p  = qi * Rp1 + ((qi * qi - qi) >> 1) + d - Rh - u * u;
            atomicAdd(&hist[p], vf);      // ds_add_f32 (no return)
        }
    };

    const int n4 = n_photons >> 2;       // 4-photon groups
    const f32x4* __restrict__ px = (const f32x4*)x;
    const f32x4* __restrict__ py = (const f32x4*)y;
    const f32x4* __restrict__ pv = (const f32x4*)vals;

    // ---- block-chunked contiguous walk + 3-deep prefetch ring ----
    const int C4 = (n4 + gridDim.x - 1) / gridDim.x;   // groups per block
    const int g0 = blockIdx.x * C4;
    const int g1 = min(g0 + C4, n4);
    const int BS = blockDim.x;

    f32x4 x0, y0, v0, x1, y1, v1, x2, y2, v2;

#define LOADS(S, idx) do { int _i = (idx); \
        x##S = __builtin_nontemporal_load(&px[_i]); \
        y##S = __builtin_nontemporal_load(&py[_i]); \
        v##S = __builtin_nontemporal_load(&pv[_i]); } while (0)
#define PROC(S) do { \
        process(x##S.x, y##S.x, v##S.x); \
        process(x##S.y, y##S.y, v##S.y); \
        process(x##S.z, y##S.z, v##S.z); \
        process(x##S.w, y##S.w, v##S.w); } while (0)
#define BODY(S) \
        if (g >= g1) break; \
        PROC(S); \
        { int pf = g + 3 * BS; if (pf < g1) LOADS(S, pf); } \
        g += BS;

    int g = g0 + threadIdx.x;
    if (g + 0 * BS < g1) LOADS(0, g + 0 * BS);
    if (g + 1 * BS < g1) LOADS(1, g + 1 * BS);
    if (g + 2 * BS < g1) LOADS(2, g + 2 * BS);

    for (;;) {
        BODY(0)
        BODY(1)
        BODY(2)
    }
#undef BODY
#undef PROC
#undef LOADS

    // photon tail (n_photons % 4)
    {
        int t0 = (n4 << 2) + blockIdx.x * blockDim.x + threadIdx.x;
        int ts = gridDim.x * blockDim.x;
        for (int t = t0; t < n_photons; t += ts)
            process(x[t], y[t], vals[t]);
    }

    __syncthreads();
    if (flush_mode == 2) {
        float* dst = flush_dst + (size_t)blockIdx.x * n_pixels;
        for (int k = threadIdx.x; k < n_pixels; k += blockDim.x)
            dst[k] = hist[k];
    } else {
        for (int k = threadIdx.x; k < n_pixels; k += blockDim.x) {
            float h = hist[k];
            if (h != 0.0f) atomicAdd(&flush_dst[k], h);
        }
    }
}

extern "C" void kernel_launch(void* const* d_in, const int* in_sizes, int n_in,
                              void* d_out, int out_size, void* d_ws, size_t ws_size,
                              hipStream_t stream) {
    const float* x      = (const float*)d_in[0];
    const float* y      = (const float*)d_in[1];
    const float* vals   = (const float*)d_in[2];
    const float* hexs   = (const float*)d_in[4];
    const float* qoff   = (const float*)d_in[5];
    const float* roff   = (const float*)d_in[6];
    const int*   qmin   = (const int*)d_in[7];
    const int*   rmin   = (const int*)d_in[8];

    const int n_photons = in_sizes[0];
    const int lut_elems = in_sizes[3];
    const int Q  = (int)(0.5 + sqrt((double)lut_elems));  // 49
    const int Rh = (Q - 1) / 2;                           // 24
    const int n_pixels = out_size;

    float* out = (float*)d_out;
    float* partials = (float*)d_ws;

    const size_t lds_bytes = (size_t)n_pixels * sizeof(float);
    const size_t part_elems = (size_t)BIN_BLOCKS * (size_t)n_pixels;

    if (ws_size >= part_elems * sizeof(float)) {
        hex_zero_kernel<<<(n_pixels + 255) / 256, 256, 0, stream>>>(out, n_pixels);
        hex_bin_kernel<<<BIN_BLOCKS, BIN_THREADS, lds_bytes, stream>>>(
            x, y, vals, hexs, qoff, roff, qmin, rmin,
            Rh, n_pixels, n_photons, partials, 2);
        dim3 rgrid((n_pixels + 255) / 256, BIN_BLOCKS / RED_GROUP);
        hex_reduce_kernel<<<rgrid, 256, 0, stream>>>(
            partials, out, n_pixels, BIN_BLOCKS);
    } else {
        hex_zero_kernel<<<(n_pixels + 255) / 256, 256, 0, stream>>>(out, n_pixels);
        hex_bin_kernel<<<BIN_BLOCKS, BIN_THREADS, lds_bytes, stream>>>(
            x, y, vals, hexs, qoff, roff, qmin, rmin,
            Rh, n_pixels, n_photons, out, 0);
    }
}